// Round 23
// baseline (23.129 us; speedup 1.0000x reference)
//
#include <hip/hip_runtime.h>
#include <hip/hip_bf16.h>

// MoE: out[b] = inp[b] @ weight[gate[b]].T
// inp: [4096,512] f32, gate: [4096] int, weight: [32,512,512] f32, out: [4096,512] f32
// Round 23: DOUBLE-BUFFERED K-loop -- one lgkm-drain + one barrier per iteration
// (4 events vs r22's 7), race-free by construction: COMPUTE(buf cur) and
// WRITE(buf next) touch disjoint LDS and share one scheduling region; the
// end-of-iter lgkmcnt(0) drains BOTH reads and writes before the barrier, so
// any read of buf X and the next write of buf X are barrier+drain separated.
// Depth-1 pinned prefetch kept (r12's depth-2 poison avoided). LDS 64KB ->
// 2 blocks/CU: this round A/Bs sync-economy vs residency at fixed correctness.
// Rest r22-verbatim: BK=128/NKT=4, 2-barrier prep, 16B ds_writes, XOR-swizzle,
// TMAX=3/grid 768, clamped pad rows, bijective XCD-chunk swizzle.

#define NE     32
#define NBATCH 4096
#define KF     512
#define NF     512
#define BM     64
#define BN     64
#define BK     128
#define NKT    (KF / BK)     // 4
#define TMAX   3
#define NCHUNK 64
#define NWG    (8 * NE * TMAX)  // 768, %8==0 -> bijective XCD swizzle
#define BUFB   ((BM + BN) * BK * 2)  // 32KB per buffer

typedef __attribute__((ext_vector_type(8))) short bf16x8;
typedef __attribute__((ext_vector_type(4))) float f32x4;

__device__ __forceinline__ unsigned cvt2(float lo, float hi) {
    __hip_bfloat162 h = __float22bfloat162_rn(make_float2(lo, hi));
    return *reinterpret_cast<unsigned*>(&h);   // v_cvt_pk_bf16_f32
}

// XOR swizzle within [row][128 bf16] (256B row stride); same bijection write+read.
__device__ __forceinline__ int swz(int row, int col_b) {
    return (row * 256 + col_b) ^ ((row & 7) << 4);
}

__global__ __launch_bounds__(256)
void moe_fused(const float* __restrict__ inp,
               const int* __restrict__ gate,
               const float* __restrict__ weight,
               float* __restrict__ out) {
    // bijective XCD-chunk swizzle (768 blocks, 8 XCDs, 96/chunk): XCD k owns
    // experts [4k,4k+4) -> W panels + token rows pinned in that L2.
    const int bid = blockIdx.x;
    const int swb = (bid & 7) * (NWG / 8) + (bid >> 3);
    const int nb    = swb & 7;
    const int y     = swb >> 3;          // 0..95
    const int e     = y / 3;
    const int local = y - e * 3;

    __shared__ __align__(16) unsigned char lds[2 * BUFB];  // 64KB double buffer
    __shared__ int srow[BM];
    __shared__ int chunkinfo[NCHUNK];

    const int tid  = threadIdx.x;
    const int lane = tid & 63;
    const int wid  = tid >> 6;

    // staging map (16B granule): slot s = i*256+tid -> row = (tid>>4) + 16*i,
    // 16B of bf16 (= 2 float4 of source) at float col (tid&15)*8
    const int srow_r = tid >> 4;         // 0..15
    const int c8     = (tid & 15) * 8;   // float offset of first float4
    const int nblk   = nb * BN;
    const float* wbase = weight + (size_t)e * (NF * KF) + (size_t)nblk * KF;

    float4 ra[8], rw[8];                 // [2i],[2i+1] = row-slot i's two float4s

    // ---- W tile-0 issued BEFORE prep: only needs e; latency hides under prep ----
#pragma unroll
    for (int i = 0; i < 4; ++i) {
        int r = srow_r + 16 * i;
        rw[2 * i]     = *(const float4*)(wbase + (size_t)r * KF + c8);
        rw[2 * i + 1] = *(const float4*)(wbase + (size_t)r * KF + c8 + 4);
    }
    asm volatile("" ::: "memory");       // pin: issue now, don't sink into prep

    // ---- self-prep: int4 gate loads + mask rank + per-wave redundant scan ----
    // thread owns gates [tid*16, tid*16+16), all inside chunk tid>>2
    int4 gv[4];
#pragma unroll
    for (int j = 0; j < 4; ++j)
        gv[j] = ((const int4*)gate)[tid * 4 + j];

    unsigned mask = 0;
#pragma unroll
    for (int j = 0; j < 4; ++j) {
        if (gv[j].x == e) mask |= 1u << (j * 4 + 0);
        if (gv[j].y == e) mask |= 1u << (j * 4 + 1);
        if (gv[j].z == e) mask |= 1u << (j * 4 + 2);
        if (gv[j].w == e) mask |= 1u << (j * 4 + 3);
    }
    const int cnt = __popc(mask);

    // inclusive scan over the 4 threads of this chunk (lanes grouped by 4)
    int xs = cnt;
    {
        int u = __shfl_up(xs, 1, 4); if ((lane & 3) >= 1) xs += u;
        u     = __shfl_up(xs, 2, 4); if ((lane & 3) >= 2) xs += u;
    }
    const int pre = xs - cnt;            // exclusive prefix within chunk
    if ((lane & 3) == 3) chunkinfo[tid >> 2] = xs;   // chunk total
    if (tid < BM) srow[tid] = -1;
    __syncthreads();                     // barrier 1: chunk counts + srow init

    // per-wave redundant scan of all 64 chunk counts (no wave-0 serialization)
    int cc = chunkinfo[lane];
    int x  = cc;
#pragma unroll
    for (int d = 1; d < 64; d <<= 1) {
        int u = __shfl_up(x, d, 64);
        if (lane >= d) x += u;
    }
    const int excl  = x - cc;            // lane l holds exclusive base of chunk l
    const int total = __shfl(x, 63, 64);

    // shfl with ALL lanes active (r18 bug fix: inactive source = undefined)
    const int chunkbase = __shfl(excl, tid >> 2, 64);

    const int m0 = local * BM;
    if (m0 >= total) return;             // block-uniform exit (no barrier pending)

    // scatter: rank = own-chunk base + within-chunk prefix + intra-thread order
    if (mask) {
        int rr = chunkbase + pre;
        unsigned mm = mask;
        while (mm) {
            int j = __ffs(mm) - 1;
            mm &= mm - 1;
            if (rr >= m0 && rr < m0 + BM)
                srow[rr - m0] = tid * 16 + j;
            ++rr;
        }
    }
    __syncthreads();                     // barrier 2: srow ready

    const int wm = wid & 1;
    const int wn = wid >> 1;

    int arow[4];
    const float* ap[4];
#pragma unroll
    for (int i = 0; i < 4; ++i) {
        arow[i] = srow[srow_r + 16 * i];
        // clamp pad rows to row 0: real data, outputs never stored (r14-validated)
        ap[i] = inp + (size_t)(arow[i] < 0 ? 0 : arow[i]) * KF + c8;
    }

#define LOADA(T) do { const int k0 = (T) * BK;                                       \
    _Pragma("unroll") for (int i = 0; i < 4; ++i) {                                  \
        ra[2 * i]     = *(const float4*)(ap[i] + k0);                                \
        ra[2 * i + 1] = *(const float4*)(ap[i] + k0 + 4); } } while (0)

#define LOADW(T) do { const int k0 = (T) * BK;                                       \
    _Pragma("unroll") for (int i = 0; i < 4; ++i) {                                  \
        int r = srow_r + 16 * i;                                                     \
        rw[2 * i]     = *(const float4*)(wbase + (size_t)r * KF + k0 + c8);          \
        rw[2 * i + 1] = *(const float4*)(wbase + (size_t)r * KF + k0 + c8 + 4); } } while (0)

#define WRITE_TILE(B) do { const int cb = (tid & 15) * 16;                           \
    unsigned char* Lb = lds + (B) * BUFB;                                            \
    _Pragma("unroll") for (int i = 0; i < 4; ++i) {                                  \
        int r = srow_r + 16 * i;                                                     \
        uint4 p = make_uint4(cvt2(ra[2*i].x,   ra[2*i].y),                           \
                             cvt2(ra[2*i].z,   ra[2*i].w),                           \
                             cvt2(ra[2*i+1].x, ra[2*i+1].y),                         \
                             cvt2(ra[2*i+1].z, ra[2*i+1].w));                        \
        *(uint4*)(Lb + swz(r, cb)) = p; }                                            \
    _Pragma("unroll") for (int i = 0; i < 4; ++i) {                                  \
        int r = srow_r + 16 * i;                                                     \
        uint4 p = make_uint4(cvt2(rw[2*i].x,   rw[2*i].y),                           \
                             cvt2(rw[2*i].z,   rw[2*i].w),                           \
                             cvt2(rw[2*i+1].x, rw[2*i+1].y),                         \
                             cvt2(rw[2*i+1].z, rw[2*i+1].w));                        \
        *(uint4*)(Lb + 16384 + swz(r, cb)) = p; } } while (0)

    f32x4 acc[2][2];
#pragma unroll
    for (int mi = 0; mi < 2; ++mi)
#pragma unroll
        for (int ni = 0; ni < 2; ++ni) acc[mi][ni] = (f32x4)(0.f);

#define COMPUTE(B) do { const unsigned char* Lb = lds + (B) * BUFB;                  \
    _Pragma("unroll") for (int kk = 0; kk < 4; ++kk) {                               \
        const int kb = kk * 64 + 16 * (lane >> 4);                                   \
        bf16x8 af[2], bfr[2];                                                        \
        _Pragma("unroll") for (int mi = 0; mi < 2; ++mi) {                           \
            int r = wm * 32 + mi * 16 + (lane & 15);                                 \
            af[mi] = *(const bf16x8*)(Lb + swz(r, kb)); }                            \
        _Pragma("unroll") for (int ni = 0; ni < 2; ++ni) {                           \
            int r = wn * 32 + ni * 16 + (lane & 15);                                 \
            bfr[ni] = *(const bf16x8*)(Lb + 16384 + swz(r, kb)); }                   \
        _Pragma("unroll") for (int mi = 0; mi < 2; ++mi)                             \
        _Pragma("unroll") for (int ni = 0; ni < 2; ++ni)                             \
            acc[mi][ni] = __builtin_amdgcn_mfma_f32_16x16x32_bf16(                   \
                af[mi], bfr[ni], acc[mi][ni], 0, 0, 0); } } while (0)

    // ---- double-buffered K-loop: ONE drain+barrier per iteration (4 total) ----
    // prologue: stage tile 0 into buf0 (A(0) issues here; W(0) in flight)
    LOADA(0);
    asm volatile("" ::: "memory");
    WRITE_TILE(0);                       // vmcnt waits tile-0 loads
    asm volatile("s_waitcnt lgkmcnt(0)" ::: "memory");
    __builtin_amdgcn_s_barrier();        // buf0 ready

    for (int t = 0; t < NKT; ++t) {
        if (t + 1 < NKT) {
            LOADA(t + 1);                // issue early: COMPUTE covers latency
            LOADW(t + 1);
            asm volatile("" ::: "memory");  // PIN: loads may not sink below
        }
        COMPUTE(t & 1);                  // reads buf[cur]
        if (t + 1 < NKT) {
            WRITE_TILE((t + 1) & 1);     // writes OTHER buf: overlaps COMPUTE region
            // one drain covers COMPUTE's reads AND WRITE's writes (all lgkm ops)
            asm volatile("s_waitcnt lgkmcnt(0)" ::: "memory");
            __builtin_amdgcn_s_barrier();
        }
        // t == NKT-1: nothing after COMPUTE touches staged LDS -> no barrier
    }
#undef LOADA
#undef LOADW
#undef WRITE_TILE
#undef COMPUTE

    // ---- epilogue: D frag col=lane&15 (n), row=(lane>>4)*4+q (m) ----
#pragma unroll
    for (int mi = 0; mi < 2; ++mi)
#pragma unroll
        for (int q = 0; q < 4; ++q) {
            int m = wm * 32 + mi * 16 + (lane >> 4) * 4 + q;
            int row = srow[m];
            if (row >= 0) {
#pragma unroll
                for (int ni = 0; ni < 2; ++ni)
                    out[(size_t)row * NF + nblk + wn * 32 + ni * 16 + (lane & 15)]
                        = acc[mi][ni][q];
            }
        }
}

extern "C" void kernel_launch(void* const* d_in, const int* in_sizes, int n_in,
                              void* d_out, int out_size, void* d_ws, size_t ws_size,
                              hipStream_t stream) {
    const float* inp    = (const float*)d_in[0];
    const int*   gate   = (const int*)d_in[1];
    const float* weight = (const float*)d_in[2];
    float*       out    = (float*)d_out;

    moe_fused<<<NWG, 256, 0, stream>>>(inp, gate, weight, out);
}

// Round 24
// 18.751 us; speedup vs baseline: 1.2335x; 1.2335x over previous
//
#include <hip/hip_runtime.h>
#include <hip/hip_bf16.h>

// MoE: out[b] = inp[b] @ weight[gate[b]].T
// inp: [4096,512] f32, gate: [4096] int, weight: [32,512,512] f32, out: [4096,512] f32
// Round 24: BK=64 DOUBLE-BUFFER -- the unmeasured quadrant. 2 x 16KB buffers =
// 32KB total: same residency as r22 (4 blocks/CU) but ONE drain+barrier per
// iteration (race-free: reads of buf X and next writes of buf X are separated
// by a fully-drained barrier; lgkmcnt counts both ds_reads and ds_writes), and
// WRITE(t+1) overlaps COMPUTE(t)'s MFMA stream. NKT=8.
// r22-validated parts verbatim: mask prep (2 barriers, hoisted shfl), W tile-0
// pre-prep issue, pinned pre-COMPUTE load issue, 16B ds_writes, XOR swizzle,
// TMAX=3/grid 768, clamped pad rows, bijective XCD-chunk swizzle.

#define NE     32
#define NBATCH 4096
#define KF     512
#define NF     512
#define BM     64
#define BN     64
#define BK     64
#define NKT    (KF / BK)     // 8
#define TMAX   3
#define NCHUNK 64
#define NWG    (8 * NE * TMAX)  // 768, %8==0 -> bijective XCD swizzle
#define BUFB   ((BM + BN) * BK * 2)  // 16KB per buffer

typedef __attribute__((ext_vector_type(8))) short bf16x8;
typedef __attribute__((ext_vector_type(4))) float f32x4;

__device__ __forceinline__ unsigned cvt2(float lo, float hi) {
    __hip_bfloat162 h = __float22bfloat162_rn(make_float2(lo, hi));
    return *reinterpret_cast<unsigned*>(&h);   // v_cvt_pk_bf16_f32
}

// XOR swizzle within [row][64 bf16] (128B row stride); same bijection write+read.
// Reads: 16 lanes x rows r..r+15 at one kb -> 8 distinct 16B slots -> 2-way (free).
__device__ __forceinline__ int swz(int row, int col_b) {
    return row * 128 + (col_b ^ ((row & 7) << 4));
}

__global__ __launch_bounds__(256)
void moe_fused(const float* __restrict__ inp,
               const int* __restrict__ gate,
               const float* __restrict__ weight,
               float* __restrict__ out) {
    // bijective XCD-chunk swizzle (768 blocks, 8 XCDs, 96/chunk): XCD k owns
    // experts [4k,4k+4) -> W panels + token rows pinned in that L2.
    const int bid = blockIdx.x;
    const int swb = (bid & 7) * (NWG / 8) + (bid >> 3);
    const int nb    = swb & 7;
    const int y     = swb >> 3;          // 0..95
    const int e     = y / 3;
    const int local = y - e * 3;

    __shared__ __align__(16) unsigned char lds[2 * BUFB];  // 32KB double buffer
    __shared__ int srow[BM];
    __shared__ int chunkinfo[NCHUNK];

    const int tid  = threadIdx.x;
    const int lane = tid & 63;
    const int wid  = tid >> 6;

    // staging map (16B granule): thread covers rows (tid>>3)+32*i (i<2) at
    // float col (tid&7)*8 (16 consecutive bf16 after cvt).
    const int srow_r = tid >> 3;         // 0..31
    const int c8     = (tid & 7) * 8;    // float offset of first float4
    const int nblk   = nb * BN;
    const float* wbase = weight + (size_t)e * (NF * KF) + (size_t)nblk * KF;

    float4 ra[4], rw[4];                 // [2i],[2i+1] = row-slot i's two float4s

    // ---- W tile-0 issued BEFORE prep: only needs e; latency hides under prep ----
#pragma unroll
    for (int i = 0; i < 2; ++i) {
        int r = srow_r + 32 * i;
        rw[2 * i]     = *(const float4*)(wbase + (size_t)r * KF + c8);
        rw[2 * i + 1] = *(const float4*)(wbase + (size_t)r * KF + c8 + 4);
    }
    asm volatile("" ::: "memory");       // pin: issue now, don't sink into prep

    // ---- self-prep: int4 gate loads + mask rank + per-wave redundant scan ----
    // thread owns gates [tid*16, tid*16+16), all inside chunk tid>>2
    int4 gv[4];
#pragma unroll
    for (int j = 0; j < 4; ++j)
        gv[j] = ((const int4*)gate)[tid * 4 + j];

    unsigned mask = 0;
#pragma unroll
    for (int j = 0; j < 4; ++j) {
        if (gv[j].x == e) mask |= 1u << (j * 4 + 0);
        if (gv[j].y == e) mask |= 1u << (j * 4 + 1);
        if (gv[j].z == e) mask |= 1u << (j * 4 + 2);
        if (gv[j].w == e) mask |= 1u << (j * 4 + 3);
    }
    const int cnt = __popc(mask);

    // inclusive scan over the 4 threads of this chunk (lanes grouped by 4)
    int xs = cnt;
    {
        int u = __shfl_up(xs, 1, 4); if ((lane & 3) >= 1) xs += u;
        u     = __shfl_up(xs, 2, 4); if ((lane & 3) >= 2) xs += u;
    }
    const int pre = xs - cnt;            // exclusive prefix within chunk
    if ((lane & 3) == 3) chunkinfo[tid >> 2] = xs;   // chunk total
    if (tid < BM) srow[tid] = -1;
    __syncthreads();                     // barrier 1: chunk counts + srow init

    // per-wave redundant scan of all 64 chunk counts (no wave-0 serialization)
    int cc = chunkinfo[lane];
    int x  = cc;
#pragma unroll
    for (int d = 1; d < 64; d <<= 1) {
        int u = __shfl_up(x, d, 64);
        if (lane >= d) x += u;
    }
    const int excl  = x - cc;            // lane l holds exclusive base of chunk l
    const int total = __shfl(x, 63, 64);

    // shfl with ALL lanes active (r18 bug fix: inactive source = undefined)
    const int chunkbase = __shfl(excl, tid >> 2, 64);

    const int m0 = local * BM;
    if (m0 >= total) return;             // block-uniform exit (no barrier pending)

    // scatter: rank = own-chunk base + within-chunk prefix + intra-thread order
    if (mask) {
        int rr = chunkbase + pre;
        unsigned mm = mask;
        while (mm) {
            int j = __ffs(mm) - 1;
            mm &= mm - 1;
            if (rr >= m0 && rr < m0 + BM)
                srow[rr - m0] = tid * 16 + j;
            ++rr;
        }
    }
    __syncthreads();                     // barrier 2: srow ready

    const int wm = wid & 1;
    const int wn = wid >> 1;

    int arow[2];
    const float* ap[2];
#pragma unroll
    for (int i = 0; i < 2; ++i) {
        arow[i] = srow[srow_r + 32 * i];
        // clamp pad rows to row 0: real data, outputs never stored (r14-validated)
        ap[i] = inp + (size_t)(arow[i] < 0 ? 0 : arow[i]) * KF + c8;
    }

#define LOADA(T) do { const int k0 = (T) * BK;                                       \
    _Pragma("unroll") for (int i = 0; i < 2; ++i) {                                  \
        ra[2 * i]     = *(const float4*)(ap[i] + k0);                                \
        ra[2 * i + 1] = *(const float4*)(ap[i] + k0 + 4); } } while (0)

#define LOADW(T) do { const int k0 = (T) * BK;                                       \
    _Pragma("unroll") for (int i = 0; i < 2; ++i) {                                  \
        int r = srow_r + 32 * i;                                                     \
        rw[2 * i]     = *(const float4*)(wbase + (size_t)r * KF + k0 + c8);          \
        rw[2 * i + 1] = *(const float4*)(wbase + (size_t)r * KF + k0 + c8 + 4); } } while (0)

#define WRITE_TILE(B) do { const int cb = (tid & 7) * 16;                            \
    unsigned char* Lb = lds + (B) * BUFB;                                            \
    _Pragma("unroll") for (int i = 0; i < 2; ++i) {                                  \
        int r = srow_r + 32 * i;                                                     \
        uint4 p = make_uint4(cvt2(ra[2*i].x,   ra[2*i].y),                           \
                             cvt2(ra[2*i].z,   ra[2*i].w),                           \
                             cvt2(ra[2*i+1].x, ra[2*i+1].y),                         \
                             cvt2(ra[2*i+1].z, ra[2*i+1].w));                        \
        *(uint4*)(Lb + swz(r, cb)) = p; }                                            \
    _Pragma("unroll") for (int i = 0; i < 2; ++i) {                                  \
        int r = srow_r + 32 * i;                                                     \
        uint4 p = make_uint4(cvt2(rw[2*i].x,   rw[2*i].y),                           \
                             cvt2(rw[2*i].z,   rw[2*i].w),                           \
                             cvt2(rw[2*i+1].x, rw[2*i+1].y),                         \
                             cvt2(rw[2*i+1].z, rw[2*i+1].w));                        \
        *(uint4*)(Lb + 8192 + swz(r, cb)) = p; } } while (0)

    f32x4 acc[2][2];
#pragma unroll
    for (int mi = 0; mi < 2; ++mi)
#pragma unroll
        for (int ni = 0; ni < 2; ++ni) acc[mi][ni] = (f32x4)(0.f);

#define COMPUTE(B) do { const unsigned char* Lb = lds + (B) * BUFB;                  \
    _Pragma("unroll") for (int kk = 0; kk < 2; ++kk) {                               \
        const int kb = kk * 64 + 16 * (lane >> 4);                                   \
        bf16x8 af[2], bfr[2];                                                        \
        _Pragma("unroll") for (int mi = 0; mi < 2; ++mi) {                           \
            int r = wm * 32 + mi * 16 + (lane & 15);                                 \
            af[mi] = *(const bf16x8*)(Lb + swz(r, kb)); }                            \
        _Pragma("unroll") for (int ni = 0; ni < 2; ++ni) {                           \
            int r = wn * 32 + ni * 16 + (lane & 15);                                 \
            bfr[ni] = *(const bf16x8*)(Lb + 8192 + swz(r, kb)); }                    \
        _Pragma("unroll") for (int mi = 0; mi < 2; ++mi)                             \
        _Pragma("unroll") for (int ni = 0; ni < 2; ++ni)                             \
            acc[mi][ni] = __builtin_amdgcn_mfma_f32_16x16x32_bf16(                   \
                af[mi], bfr[ni], acc[mi][ni], 0, 0, 0); } } while (0)

    // ---- double-buffered K-loop: ONE drain+barrier per iteration ----
    // Race-freedom: reads of buf X (iter t) drain at iter t's end-barrier;
    // the next write to buf X is at iter t+1, after that barrier. Writes of
    // buf Y (iter t) drain at the same barrier; reads of Y are at t+1. QED.
    LOADA(0);                            // W tile 0 in flight since kernel entry
    asm volatile("" ::: "memory");
    WRITE_TILE(0);                       // vmcnt waits tile-0 loads only
    asm volatile("s_waitcnt lgkmcnt(0)" ::: "memory");
    __builtin_amdgcn_s_barrier();        // buf0 ready

    for (int t = 0; t < NKT; ++t) {
        if (t + 1 < NKT) {
            LOADA(t + 1);                // issue early: COMPUTE covers latency
            LOADW(t + 1);
            asm volatile("" ::: "memory");  // PIN: loads may not sink below
        }
        COMPUTE(t & 1);                  // reads buf[cur]
        if (t + 1 < NKT) {
            WRITE_TILE((t + 1) & 1);     // disjoint buf: overlaps MFMA stream
            asm volatile("s_waitcnt lgkmcnt(0)" ::: "memory");  // reads+writes
            __builtin_amdgcn_s_barrier();
        }
    }
#undef LOADA
#undef LOADW
#undef WRITE_TILE
#undef COMPUTE

    // ---- epilogue: D frag col=lane&15 (n), row=(lane>>4)*4+q (m) ----
#pragma unroll
    for (int mi = 0; mi < 2; ++mi)
#pragma unroll
        for (int q = 0; q < 4; ++q) {
            int m = wm * 32 + mi * 16 + (lane >> 4) * 4 + q;
            int row = srow[m];
            if (row >= 0) {
#pragma unroll
                for (int ni = 0; ni < 2; ++ni)
                    out[(size_t)row * NF + nblk + wn * 32 + ni * 16 + (lane & 15)]
                        = acc[mi][ni][q];
            }
        }
}

extern "C" void kernel_launch(void* const* d_in, const int* in_sizes, int n_in,
                              void* d_out, int out_size, void* d_ws, size_t ws_size,
                              hipStream_t stream) {
    const float* inp    = (const float*)d_in[0];
    const int*   gate   = (const int*)d_in[1];
    const float* weight = (const float*)d_in[2];
    float*       out    = (float*)d_out;

    moe_fused<<<NWG, 256, 0, stream>>>(inp, gate, weight, out);
}